// Round 1
// baseline (274.225 us; speedup 1.0000x reference)
//
#include <hip/hip_runtime.h>
#include <math.h>

typedef _Float16 v8h __attribute__((ext_vector_type(8)));
typedef float v4f __attribute__((ext_vector_type(4)));

#define UNITS    50
#define K3       150
#define FDIM     64
#define TSTEPS   128
#define BATCH    4096
#define NB       16     // batch rows per block tile (MFMA M)
#define H16S     72     // halves per h row (50 h + slot50=1.0 + pad); 144 B stride, 16B-aligned
#define H32S     52

#if __has_builtin(__builtin_amdgcn_exp2f)
__device__ __forceinline__ float fast_exp2(float x) { return __builtin_amdgcn_exp2f(x); }
#else
__device__ __forceinline__ float fast_exp2(float x) { return exp2f(x); }
#endif
#if __has_builtin(__builtin_amdgcn_rcpf)
__device__ __forceinline__ float fast_rcp(float x) { return __builtin_amdgcn_rcpf(x); }
#else
__device__ __forceinline__ float fast_rcp(float x) { return 1.0f / x; }
#endif

// 4 waves per block, one 16-batch tile per block. Wave nt owns u-columns
// nt*16..nt*16+15 and computes ALL THREE gates for them. Waves couple only
// through the f16 h exchange (ping-pong LDS buffers).
//
// This version removes the structural per-step stall of __syncthreads():
//  - raw s_barrier + manual "s_waitcnt lgkmcnt(0)" (NO vmcnt(0) drain, so the
//    x prefetch global loads stay in flight across the barrier — T4 pattern)
//  - the 6 x-dependent MFMAs + f32->f16 conversion for step t+1 are issued in
//    step t's pre-barrier shadow; post-barrier critical path is only
//    ds_read(h) -> 2-deep MFMA -> gate math -> ds_write.
//  - x prefetch distance = 2 steps (ping-pong named reg buffers; named arrays
//    with compile-time indices so nothing spills to scratch).
__global__ __launch_bounds__(256, 1)
void gru_4w(const float* __restrict__ x, const float* __restrict__ W,
            const float* __restrict__ U, const float* __restrict__ bv,
            const float* __restrict__ Wd, const float* __restrict__ bd,
            float* __restrict__ out) {
    __shared__ _Float16 hs16[2][NB * H16S];   // ping-pong h state (f16)
    __shared__ float    hs32[NB * H32S];      // epilogue only

    const int tid  = threadIdx.x;
    const int nt   = tid >> 6;          // wave id = ntile (wave-uniform)
    const int lane = tid & 63;
    const int n    = lane & 15;
    const int quad = lane >> 4;
    const int b0   = blockIdx.x * NB;
    const int c    = nt * 16 + n;       // this lane's unit column (>=50 for tail of wave 3)

    // ---- init both h buffers: zeros, constant 1.0 at slot u=50 (bias-fold row) ----
    for (int i = tid; i < NB * H16S; i += 256) {
        _Float16 v = ((i % H16S) == 50) ? (_Float16)1.f : (_Float16)0.f;
        hs16[0][i] = v;
        hs16[1][i] = v;
    }

    // ---- B fragments for this wave's ntile (VGPR-resident whole kernel) ----
    // combined K rows: 0..63 = W, 64..113 = U, 114 = b[1] h-col fold, rest 0
    v8h Bz[4], Br[4], Bh[4];
    #pragma unroll
    for (int kt = 0; kt < 4; ++kt) {
        v8h fz, fr, fh;
        #pragma unroll
        for (int j = 0; j < 8; ++j) {
            const int k = kt * 32 + quad * 8 + j;
            float vz = 0.f, vr = 0.f, vh = 0.f;
            if (c < UNITS) {
                if (k < FDIM) {
                    vz = W[k * K3 + c];
                    vr = W[k * K3 + 50 + c];
                    vh = W[k * K3 + 100 + c];
                } else if (k < FDIM + UNITS) {
                    const int ur = k - FDIM;
                    vz = U[ur * K3 + c];
                    vr = U[ur * K3 + 50 + c];
                    vh = U[ur * K3 + 100 + c];
                } else if (k == FDIM + UNITS) {
                    vh = bv[250 + c];           // b[1] h-col via h-slot u=50 == 1.0
                }
            }
            fz[j] = (_Float16)vz; fr[j] = (_Float16)vr; fh[j] = (_Float16)vh;
        }
        Bz[kt] = fz; Br[kt] = fr; Bh[kt] = fh;
    }

    // ---- sigmoid-folded bias constants for this lane's column ----
    const float CE = -1.44269504f;      // sigmoid(a) = 1 / (1 + 2^(CE*a))
    float bzc = 0.f, brc = 0.f, bx = 0.f;
    if (c < UNITS) {
        bzc = CE * (bv[c]      + bv[150 + c]);
        brc = CE * (bv[50 + c] + bv[200 + c]);
        bx  = bv[100 + c];
    }

    // f32 h state in registers: h32[r] = h[m=quad*4+r][u=c]
    v4f h32 = {0.f, 0.f, 0.f, 0.f};

    const float* xbase = x + ((size_t)(b0 + n) * TSTEPS) * FDIM + quad * 8;

    // x-partial MFMAs for one step from 4 f32 quads (keeps original accumulate
    // order: A0,A1 first -> bitwise-identical numerics vs previous kernel)
    v4f az_x, ar_x, ax_x;
    auto xpart = [&](const v4f& q0, const v4f& q1, const v4f& q2, const v4f& q3) {
        v8h A0, A1;
        #pragma unroll
        for (int j = 0; j < 4; ++j) {
            A0[j]     = (_Float16)q0[j];
            A0[j + 4] = (_Float16)q1[j];
            A1[j]     = (_Float16)q2[j];
            A1[j + 4] = (_Float16)q3[j];
        }
        const v4f zero4 = {0.f, 0.f, 0.f, 0.f};
        az_x = __builtin_amdgcn_mfma_f32_16x16x32_f16(A0, Bz[0], zero4, 0, 0, 0);
        az_x = __builtin_amdgcn_mfma_f32_16x16x32_f16(A1, Bz[1], az_x,  0, 0, 0);
        ar_x = __builtin_amdgcn_mfma_f32_16x16x32_f16(A0, Br[0], zero4, 0, 0, 0);
        ar_x = __builtin_amdgcn_mfma_f32_16x16x32_f16(A1, Br[1], ar_x,  0, 0, 0);
        v4f axi = {bx, bx, bx, bx};
        ax_x = __builtin_amdgcn_mfma_f32_16x16x32_f16(A0, Bh[0], axi,  0, 0, 0);
        ax_x = __builtin_amdgcn_mfma_f32_16x16x32_f16(A1, Bh[1], ax_x, 0, 0, 0);
    };

    // ---- prologue: x(0) partials now; prefetch x(1) and x(2) into regs ----
    {
        v4f q0 = *(const v4f*)(xbase + 0);
        v4f q1 = *(const v4f*)(xbase + 4);
        v4f q2 = *(const v4f*)(xbase + 32);
        v4f q3 = *(const v4f*)(xbase + 36);
        xpart(q0, q1, q2, q3);
    }
    v4f pxO[4], pxE[4];   // pxO = x(t+1) for even t, pxE = x(t+1) for odd t
    {
        const float* x1 = xbase + (size_t)1 * FDIM;
        pxO[0] = *(const v4f*)(x1 + 0);  pxO[1] = *(const v4f*)(x1 + 4);
        pxO[2] = *(const v4f*)(x1 + 32); pxO[3] = *(const v4f*)(x1 + 36);
        const float* x2 = xbase + (size_t)2 * FDIM;
        pxE[0] = *(const v4f*)(x2 + 0);  pxE[1] = *(const v4f*)(x2 + 4);
        pxE[2] = *(const v4f*)(x2 + 32); pxE[3] = *(const v4f*)(x2 + 36);
    }

    __syncthreads();   // one-time: hs16 init visible (vmcnt drain here is fine)

    auto step = [&](int t, v4f (&px)[4]) {
        const _Float16* hrd = hs16[t & 1];
        _Float16*       hwr = hs16[(t + 1) & 1];

        // post-barrier critical path: h fragment read + 2-deep MFMA chains
        v8h A2 = *(const v8h*)(&hrd[n * H16S + quad * 8]);       // k 64..95  (h 0..31)
        v8h A3 = *(const v8h*)(&hrd[n * H16S + 32 + quad * 8]);  // k 96..127 (h 32..49, 1.0, 0s)

        const v4f zero4 = {0.f, 0.f, 0.f, 0.f};
        v4f az = __builtin_amdgcn_mfma_f32_16x16x32_f16(A2, Bz[2], az_x, 0, 0, 0);
        az     = __builtin_amdgcn_mfma_f32_16x16x32_f16(A3, Bz[3], az,   0, 0, 0);
        v4f ar = __builtin_amdgcn_mfma_f32_16x16x32_f16(A2, Br[2], ar_x, 0, 0, 0);
        ar     = __builtin_amdgcn_mfma_f32_16x16x32_f16(A3, Br[3], ar,   0, 0, 0);
        v4f ah = __builtin_amdgcn_mfma_f32_16x16x32_f16(A2, Bh[2], zero4, 0, 0, 0);
        ah     = __builtin_amdgcn_mfma_f32_16x16x32_f16(A3, Bh[3], ah,    0, 0, 0);
        v4f ax = ax_x;

        // shadow work for step t+1: f32->f16 convert + 6 x-MFMAs + prefetch x(t+3)
        // (independent of this step's gate math; scheduler interleaves freely)
        if (t + 1 < TSTEPS) {
            xpart(px[0], px[1], px[2], px[3]);
            if (t + 3 < TSTEPS) {
                const float* xp = xbase + (size_t)(t + 3) * FDIM;
                px[0] = *(const v4f*)(xp + 0);
                px[1] = *(const v4f*)(xp + 4);
                px[2] = *(const v4f*)(xp + 32);
                px[3] = *(const v4f*)(xp + 36);
            }
        }

        // register-local gate math: 4 rows (m = quad*4 + r)
        #pragma unroll
        for (int r = 0; r < 4; ++r) {
            const float ez = fast_exp2(fmaf(az[r], CE, bzc));
            const float er = fast_exp2(fmaf(ar[r], CE, brc));
            const float pz = 1.f + ez;
            const float pr = 1.f + er;
            const float d  = fast_rcp(pz * pr);
            const float zg = d * pr;                 // sigmoid(z-pre)
            const float rg = d * pz;                 // sigmoid(r-pre)
            const float hc = fmaxf(fmaf(rg, ah[r], ax[r]), 0.f);  // ah includes b[1]
            const float hn = fmaf(zg, h32[r] - hc, hc);           // z*h + (1-z)*hc
            h32[r] = hn;
            if (c < UNITS)
                hwr[(quad * 4 + r) * H16S + c] = (_Float16)hn;
        }

        // publish h(t+1): drain LDS ops only — x prefetch stays in flight (vmcnt
        // NOT drained, unlike __syncthreads()). sched_barrier stops the next
        // iteration's ds_read from hoisting above the barrier.
        asm volatile("s_waitcnt lgkmcnt(0)" ::: "memory");
        __builtin_amdgcn_s_barrier();
        __builtin_amdgcn_sched_barrier(0);
    };

    for (int t = 0; t < TSTEPS; t += 2) {
        step(t,     pxO);
        step(t + 1, pxE);
    }

    // ---- epilogue: out[b] = h_T @ Wd + bd (exact f32 h) ----
    if (c < UNITS) {
        #pragma unroll
        for (int r = 0; r < 4; ++r)
            hs32[(quad * 4 + r) * H32S + c] = h32[r];
    }
    __syncthreads();
    if (tid < NB) {
        float acc = bd[0];
        #pragma unroll
        for (int u = 0; u < UNITS; ++u)
            acc = fmaf(hs32[tid * H32S + u], Wd[u], acc);
        out[b0 + tid] = acc;
    }
}

extern "C" void kernel_launch(void* const* d_in, const int* in_sizes, int n_in,
                              void* d_out, int out_size, void* d_ws, size_t ws_size,
                              hipStream_t stream) {
    const float* x    = (const float*)d_in[0];
    const float* W    = (const float*)d_in[1];
    const float* U    = (const float*)d_in[2];
    const float* bv   = (const float*)d_in[3];
    const float* Wd   = (const float*)d_in[4];
    const float* bd   = (const float*)d_in[5];
    float* out = (float*)d_out;

    dim3 grid(BATCH / NB);    // 256 blocks -> 1 per CU
    dim3 block(256);          // 4 waves, one per SIMD
    gru_4w<<<grid, block, 0, stream>>>(x, W, U, bv, Wd, bd, out);
}